// Round 1
// baseline (176.195 us; speedup 1.0000x reference)
//
#include <hip/hip_runtime.h>
#include <math.h>

#define KK 8
#define DD 128
#define RR 4
#define NG 5   // 1 + R groups per edge

__global__ __launch_bounds__(256) void dhg_fused(
    const float* __restrict__ feats,
    const int*   __restrict__ edge_members,
    const int*   __restrict__ adj_members,
    const float* __restrict__ wq, const float* __restrict__ bq,
    const float* __restrict__ wk, const float* __restrict__ bk,
    const float* __restrict__ wv, const float* __restrict__ bv,
    const float* __restrict__ W1, const float* __restrict__ b1,
    const float* __restrict__ W2, const float* __restrict__ b2,
    const float* __restrict__ Wfc, const float* __restrict__ bfc,
    float* __restrict__ out)
{
    __shared__ float fsh[KK][DD];     // gathered rows of current group
    __shared__ float ft[NG][DD];      // 5 group features
    __shared__ float qs[KK], ks[KK], vs[KK], di[KK];
    __shared__ float sc[NG], aw[NG];
    __shared__ float red[4];

    const int e = blockIdx.x;
    const int t = threadIdx.x;
    const int j = t >> 5;   // row 0..7
    const int l = t & 31;   // lane within row

    // per-thread slices of the q/k/v weight vectors (L1-hot)
    const float4 wq4 = *(const float4*)&wq[l * 4];
    const float4 wk4 = *(const float4*)&wk[l * 4];
    const float4 wv4 = *(const float4*)&wv[l * 4];
    const float bq0 = bq[0], bk0 = bk[0], bv0 = bv[0];

    for (int g = 0; g < NG; ++g) {
        const int vid = (g == 0) ? edge_members[e * KK + j]
                                 : adj_members[((e * RR) + (g - 1)) * KK + j];
        const float4 fv = *(const float4*)&feats[(long long)vid * DD + l * 4];
        *(float4*)&fsh[j][l * 4] = fv;

        float pq = fv.x * wq4.x + fv.y * wq4.y + fv.z * wq4.z + fv.w * wq4.w;
        float pk = fv.x * wk4.x + fv.y * wk4.y + fv.z * wk4.z + fv.w * wk4.w;
        float pv = fv.x * wv4.x + fv.y * wv4.y + fv.z * wv4.z + fv.w * wv4.w;
        #pragma unroll
        for (int m = 16; m >= 1; m >>= 1) {
            pq += __shfl_xor(pq, m);
            pk += __shfl_xor(pk, m);
            pv += __shfl_xor(pv, m);
        }
        if (l == 0) { qs[j] = pq + bq0; ks[j] = pk + bk0; vs[j] = pv + bv0; }
        __syncthreads();

        // masked 8x8 attention row per thread (t<8)
        if (t < KK) {
            const float qj = qs[t];
            float s[KK];
            float mx = -1e30f;
            #pragma unroll
            for (int l2 = 0; l2 < KK; ++l2) {
                s[l2] = qj * ks[l2];
                if (l2 != t && s[l2] > mx) mx = s[l2];
            }
            float den = 0.f, num = 0.f;
            #pragma unroll
            for (int l2 = 0; l2 < KK; ++l2) {
                if (l2 == t) continue;
                const float ex = expf(s[l2] - mx);
                den += ex;
                num += ex * vs[l2];
            }
            di[t] = tanhf(num / den);
        }
        __syncthreads();

        // group feature: ft[g][d] = sum_j di[j] * f[j][d]
        if (t < DD) {
            float acc = 0.f;
            #pragma unroll
            for (int jj = 0; jj < KK; ++jj) acc += di[jj] * fsh[jj][t];
            ft[g][t] = acc;
        }
        __syncthreads();
    }

    // EdgeConv MLP scores: thread = (group g, hidden unit m), t < 160
    if (t < NG * 32) {
        const int g = t >> 5, m = t & 31;
        float acc = b1[m];
        #pragma unroll 8
        for (int d = 0; d < DD; ++d) acc += ft[g][d] * W1[d * 32 + m];
        float p = (acc > 0.f ? acc : 0.f) * W2[m];
        #pragma unroll
        for (int mm = 16; mm >= 1; mm >>= 1) p += __shfl_xor(p, mm);
        if (m == 0) sc[g] = p + b2[0];
    }
    __syncthreads();

    // softmax over the 5 candidates (tiny, serial on thread 0)
    if (t == 0) {
        float mx = sc[0];
        #pragma unroll
        for (int g = 1; g < NG; ++g) mx = fmaxf(mx, sc[g]);
        float s = 0.f;
        #pragma unroll
        for (int g = 0; g < NG; ++g) { aw[g] = expf(sc[g] - mx); s += aw[g]; }
        const float inv = 1.f / s;
        #pragma unroll
        for (int g = 0; g < NG; ++g) aw[g] *= inv;
    }
    __syncthreads();

    // final: h[d] = sum_g aw[g]*ft[g][d]; out[c] = sigmoid(h . Wfc[:,c] + bfc[c])
    {
        const int c = t >> 7, d = t & 127;
        float hd = 0.f;
        #pragma unroll
        for (int g = 0; g < NG; ++g) hd += aw[g] * ft[g][d];
        float p = hd * Wfc[d * 2 + c];
        #pragma unroll
        for (int m = 32; m >= 1; m >>= 1) p += __shfl_xor(p, m);
        if ((t & 63) == 0) red[t >> 6] = p;   // one partial per wave
    }
    __syncthreads();
    if (t < 2) {
        const float v = red[t * 2] + red[t * 2 + 1] + bfc[t];
        out[e * 2 + t] = 1.f / (1.f + expf(-v));
    }
}

extern "C" void kernel_launch(void* const* d_in, const int* in_sizes, int n_in,
                              void* d_out, int out_size, void* d_ws, size_t ws_size,
                              hipStream_t stream) {
    const float* feats        = (const float*)d_in[0];
    const int*   edge_members = (const int*)  d_in[1];
    const int*   adj_members  = (const int*)  d_in[2];
    // d_in[3] = ids (unused), d_in[4] = epoch (unused; epoch=10 >= both warmups)
    const float* wq  = (const float*)d_in[5];
    const float* bq  = (const float*)d_in[6];
    const float* wk  = (const float*)d_in[7];
    const float* bk  = (const float*)d_in[8];
    const float* wv  = (const float*)d_in[9];
    const float* bv  = (const float*)d_in[10];
    const float* W1  = (const float*)d_in[11];
    const float* b1  = (const float*)d_in[12];
    const float* W2  = (const float*)d_in[13];
    const float* b2  = (const float*)d_in[14];
    const float* Wfc = (const float*)d_in[15];
    const float* bfc = (const float*)d_in[16];
    float* out = (float*)d_out;

    const int n_edge = in_sizes[1] / KK;   // 20000
    dhg_fused<<<n_edge, 256, 0, stream>>>(feats, edge_members, adj_members,
                                          wq, bq, wk, bk, wv, bv,
                                          W1, b1, W2, b2, Wfc, bfc, out);
}

// Round 2
// 161.466 us; speedup vs baseline: 1.0912x; 1.0912x over previous
//
#include <hip/hip_runtime.h>
#include <math.h>

#define KK 8
#define DD 128
#define RR 4
#define NG 5   // 1 + R groups per edge

__device__ __forceinline__ float readlane_f(float v, int l) {
    return __int_as_float(__builtin_amdgcn_readlane(__float_as_int(v), l));
}

__global__ __launch_bounds__(320) void dhg_fused(
    const float* __restrict__ feats,
    const int*   __restrict__ edge_members,
    const int*   __restrict__ adj_members,
    const float* __restrict__ wq, const float* __restrict__ bq,
    const float* __restrict__ wk, const float* __restrict__ bk,
    const float* __restrict__ wv, const float* __restrict__ bv,
    const float* __restrict__ W1, const float* __restrict__ b1,
    const float* __restrict__ W2, const float* __restrict__ b2,
    const float* __restrict__ Wfc, const float* __restrict__ bfc,
    float* __restrict__ out)
{
    __shared__ float fsh[NG][KK][DD];  // gathered rows, wave-private slices
    __shared__ float ft[NG][DD];       // 5 group features
    __shared__ float sc[NG], aw[NG];
    __shared__ float red[4];

    const int e    = blockIdx.x;
    const int t    = threadIdx.x;
    const int w    = t >> 6;     // wave = group 0..4
    const int lane = t & 63;
    const int j    = lane >> 3;  // row 0..7
    const int i    = lane & 7;   // 16-dim chunk index
    const int d0   = i << 4;     // chunk base

    // ---- gather one row slice (16 floats) ----
    const int vid = (w == 0) ? edge_members[e * KK + j]
                             : adj_members[((e * RR) + (w - 1)) * KK + j];
    const float* frow = &feats[(long long)vid * DD + d0];
    float4 fv0 = *(const float4*)&frow[0];
    float4 fv1 = *(const float4*)&frow[4];
    float4 fv2 = *(const float4*)&frow[8];
    float4 fv3 = *(const float4*)&frow[12];

    // stage to LDS (wave-private region)
    *(float4*)&fsh[w][j][d0 + 0]  = fv0;
    *(float4*)&fsh[w][j][d0 + 4]  = fv1;
    *(float4*)&fsh[w][j][d0 + 8]  = fv2;
    *(float4*)&fsh[w][j][d0 + 12] = fv3;

    // ---- q/k/v scalar dots (per-lane partial over 16 dims) ----
    float4 wa, wb;
    float pq, pk, pv;
    wa = *(const float4*)&wq[d0];     wb = *(const float4*)&wq[d0 + 4];
    pq  = fv0.x*wa.x + fv0.y*wa.y + fv0.z*wa.z + fv0.w*wa.w
        + fv1.x*wb.x + fv1.y*wb.y + fv1.z*wb.z + fv1.w*wb.w;
    wa = *(const float4*)&wq[d0 + 8]; wb = *(const float4*)&wq[d0 + 12];
    pq += fv2.x*wa.x + fv2.y*wa.y + fv2.z*wa.z + fv2.w*wa.w
        + fv3.x*wb.x + fv3.y*wb.y + fv3.z*wb.z + fv3.w*wb.w;

    wa = *(const float4*)&wk[d0];     wb = *(const float4*)&wk[d0 + 4];
    pk  = fv0.x*wa.x + fv0.y*wa.y + fv0.z*wa.z + fv0.w*wa.w
        + fv1.x*wb.x + fv1.y*wb.y + fv1.z*wb.z + fv1.w*wb.w;
    wa = *(const float4*)&wk[d0 + 8]; wb = *(const float4*)&wk[d0 + 12];
    pk += fv2.x*wa.x + fv2.y*wa.y + fv2.z*wa.z + fv2.w*wa.w
        + fv3.x*wb.x + fv3.y*wb.y + fv3.z*wb.z + fv3.w*wb.w;

    wa = *(const float4*)&wv[d0];     wb = *(const float4*)&wv[d0 + 4];
    pv  = fv0.x*wa.x + fv0.y*wa.y + fv0.z*wa.z + fv0.w*wa.w
        + fv1.x*wb.x + fv1.y*wb.y + fv1.z*wb.z + fv1.w*wb.w;
    wa = *(const float4*)&wv[d0 + 8]; wb = *(const float4*)&wv[d0 + 12];
    pv += fv2.x*wa.x + fv2.y*wa.y + fv2.z*wa.z + fv2.w*wa.w
        + fv3.x*wb.x + fv3.y*wb.y + fv3.z*wb.z + fv3.w*wb.w;

    // reduce over the 8 lanes of each row (masks 1,2,4 -> DPP, VALU pipe)
    #pragma unroll
    for (int m = 4; m >= 1; m >>= 1) {
        pq += __shfl_xor(pq, m);
        pk += __shfl_xor(pk, m);
        pv += __shfl_xor(pv, m);
    }
    const float q_j = pq + bq[0];
    const float bk0 = bk[0], bv0 = bv[0];

    // broadcast all rows' k,v via readlane (scalar, no LDS pipe)
    float k8[KK], v8[KK];
    #pragma unroll
    for (int r = 0; r < KK; ++r) {
        k8[r] = readlane_f(pk, r * 8) + bk0;
        v8[r] = readlane_f(pv, r * 8) + bv0;
    }

    // ---- masked softmax row j + tanh gate (all lanes redundantly) ----
    float s[KK];
    float mx = -1e30f;
    #pragma unroll
    for (int r = 0; r < KK; ++r) {
        s[r] = q_j * k8[r];
        if (r != j) mx = fmaxf(mx, s[r]);
    }
    float den = 0.f, num = 0.f;
    #pragma unroll
    for (int r = 0; r < KK; ++r) {
        const float ex = (r == j) ? 0.f : expf(s[r] - mx);
        den += ex;
        num += ex * v8[r];
    }
    const float di_j = tanhf(num / den);

    float di8[KK];
    #pragma unroll
    for (int r = 0; r < KK; ++r) di8[r] = readlane_f(di_j, r * 8);

    // ---- group feature: ft[w][d] = sum_j di[j]*f[j][d]; lane owns 2 dims ----
    asm volatile("s_waitcnt lgkmcnt(0)" ::: "memory");  // fsh writes visible in-wave
    {
        const int dpos = lane * 2;
        float a0 = 0.f, a1 = 0.f;
        #pragma unroll
        for (int r = 0; r < KK; ++r) {
            const float2 fj = *(const float2*)&fsh[w][r][dpos];
            a0 += di8[r] * fj.x;
            a1 += di8[r] * fj.y;
        }
        *(float2*)&ft[w][dpos] = make_float2(a0, a1);
    }
    asm volatile("s_waitcnt lgkmcnt(0)" ::: "memory");  // ft writes visible in-wave

    // ---- EdgeConv score for group w: relu(ft@W1+b1)@W2+b2, all 64 lanes ----
    {
        const int m = lane & 31;   // hidden unit
        const int h = lane >> 5;   // d-half
        float acc = (h == 0) ? b1[m] : 0.f;
        const float* ftg = ft[w];
        #pragma unroll 8
        for (int dd = 0; dd < 64; ++dd) {
            const int d = h * 64 + dd;
            acc += ftg[d] * W1[d * 32 + m];
        }
        acc += __shfl_xor(acc, 32);
        float p = fmaxf(acc, 0.f) * W2[m];
        #pragma unroll
        for (int mm = 16; mm >= 1; mm >>= 1) p += __shfl_xor(p, mm);
        if (lane == 0) sc[w] = p + b2[0];
    }
    __syncthreads();

    // ---- softmax over 5 candidates ----
    if (t == 0) {
        float m5 = sc[0];
        #pragma unroll
        for (int g = 1; g < NG; ++g) m5 = fmaxf(m5, sc[g]);
        float ssum = 0.f;
        float a5[NG];
        #pragma unroll
        for (int g = 0; g < NG; ++g) { a5[g] = expf(sc[g] - m5); ssum += a5[g]; }
        const float inv = 1.f / ssum;
        #pragma unroll
        for (int g = 0; g < NG; ++g) aw[g] = a5[g] * inv;
    }
    __syncthreads();

    // ---- final: h[d] = sum_g aw[g]*ft[g][d]; out[c] = sigmoid(h.Wfc[:,c]+bfc[c]) ----
    if (t < 256) {
        const int c = t >> 7, d = t & 127;
        float hd = 0.f;
        #pragma unroll
        for (int g = 0; g < NG; ++g) hd += aw[g] * ft[g][d];
        float p = hd * Wfc[d * 2 + c];
        #pragma unroll
        for (int m = 32; m >= 1; m >>= 1) p += __shfl_xor(p, m);
        if (lane == 0) red[t >> 6] = p;
    }
    __syncthreads();
    if (t < 2) {
        const float v = red[t * 2] + red[t * 2 + 1] + bfc[t];
        out[e * 2 + t] = 1.f / (1.f + expf(-v));
    }
}

extern "C" void kernel_launch(void* const* d_in, const int* in_sizes, int n_in,
                              void* d_out, int out_size, void* d_ws, size_t ws_size,
                              hipStream_t stream) {
    const float* feats        = (const float*)d_in[0];
    const int*   edge_members = (const int*)  d_in[1];
    const int*   adj_members  = (const int*)  d_in[2];
    // d_in[3] = ids (unused), d_in[4] = epoch (unused; epoch=10 >= both warmups)
    const float* wq  = (const float*)d_in[5];
    const float* bq  = (const float*)d_in[6];
    const float* wk  = (const float*)d_in[7];
    const float* bk  = (const float*)d_in[8];
    const float* wv  = (const float*)d_in[9];
    const float* bv  = (const float*)d_in[10];
    const float* W1  = (const float*)d_in[11];
    const float* b1  = (const float*)d_in[12];
    const float* W2  = (const float*)d_in[13];
    const float* b2  = (const float*)d_in[14];
    const float* Wfc = (const float*)d_in[15];
    const float* bfc = (const float*)d_in[16];
    float* out = (float*)d_out;

    const int n_edge = in_sizes[1] / KK;   // 20000
    dhg_fused<<<n_edge, 320, 0, stream>>>(feats, edge_members, adj_members,
                                          wq, bq, wk, bk, wv, bv,
                                          W1, b1, W2, b2, Wfc, bfc, out);
}

// Round 3
// 87.093 us; speedup vs baseline: 2.0231x; 1.8539x over previous
//
#include <hip/hip_runtime.h>
#include <math.h>

#define KK 8
#define DD 128
#define RR 4
#define NG 5    // 1 + R groups per edge
#define HID 32  // D/4 hidden units

// ---------------- Kernel A: per-vertex projections ----------------
// qkv4[v] = (f.wq+bq, f.wk+bk, f.wv+bv, 0)
// pfc2[v] = (f.Wfc[:,0], f.Wfc[:,1])           (no bias)
// P1[v][m] = f . W1[:,m]                        (no bias)
__global__ __launch_bounds__(256) void precompute_proj(
    const float* __restrict__ feats, int n_vert,
    const float* __restrict__ wq, const float* __restrict__ bq,
    const float* __restrict__ wk, const float* __restrict__ bk,
    const float* __restrict__ wv, const float* __restrict__ bv,
    const float* __restrict__ W1,
    const float* __restrict__ Wfc,
    float4* __restrict__ qkv4, float2* __restrict__ pfc2,
    float* __restrict__ P1)
{
    __shared__ float fsh[8][DD];   // 8 vertex rows per block
    const int t = threadIdx.x;
    const int g = t >> 5;          // vertex slot 0..7
    const int m = t & 31;
    const int v = blockIdx.x * 8 + g;
    if (v >= n_vert) return;

    // stage row: 32 threads x float4 = 128 floats (in-wave visibility only needed)
    *(float4*)&fsh[g][m * 4] = *(const float4*)&feats[(long long)v * DD + m * 4];
    asm volatile("s_waitcnt lgkmcnt(0)" ::: "memory");

    // P1 column m
    float acc = 0.f;
    #pragma unroll
    for (int d = 0; d < DD; d += 4) {
        const float4 f4 = *(const float4*)&fsh[g][d];
        acc += f4.x * W1[(d + 0) * HID + m] + f4.y * W1[(d + 1) * HID + m]
             + f4.z * W1[(d + 2) * HID + m] + f4.w * W1[(d + 3) * HID + m];
    }
    P1[(long long)v * HID + m] = acc;

    // 5 small dots: q,k,v,pfc0,pfc1 ; lane m covers dims m, m+32, m+64, m+96
    float pq = 0.f, pk = 0.f, pv = 0.f, p0 = 0.f, p1 = 0.f;
    #pragma unroll
    for (int c = 0; c < 4; ++c) {
        const int d = c * 32 + m;
        const float fv = fsh[g][d];
        pq += fv * wq[d];
        pk += fv * wk[d];
        pv += fv * wv[d];
        p0 += fv * Wfc[d * 2 + 0];
        p1 += fv * Wfc[d * 2 + 1];
    }
    #pragma unroll
    for (int mm = 16; mm >= 1; mm >>= 1) {
        pq += __shfl_xor(pq, mm);
        pk += __shfl_xor(pk, mm);
        pv += __shfl_xor(pv, mm);
        p0 += __shfl_xor(p0, mm);
        p1 += __shfl_xor(p1, mm);
    }
    if (m == 0) {
        qkv4[v] = make_float4(pq + bq[0], pk + bk[0], pv + bv[0], 0.f);
        pfc2[v] = make_float2(p0, p1);
    }
}

// ---------------- Kernel B: per-edge fusion (one wave per edge) ----------------
__global__ __launch_bounds__(256) void edge_fused(
    const int* __restrict__ edge_members,
    const int* __restrict__ adj_members,
    const float4* __restrict__ qkv4, const float2* __restrict__ pfc2,
    const float* __restrict__ P1,
    const float* __restrict__ b1, const float* __restrict__ W2,
    const float* __restrict__ b2, const float* __restrict__ bfc,
    float* __restrict__ out, int n_edge)
{
    __shared__ int   vidS[4][NG * KK];
    __shared__ float diS [4][NG * KK];
    __shared__ float ftfcS[4][NG][2];
    __shared__ float scS [4][NG];

    const int t = threadIdx.x;
    const int w = t >> 6;          // wave in block
    const int lane = t & 63;
    const int e = blockIdx.x * 4 + w;
    if (e >= n_edge) return;

    const int g = lane >> 3;       // group 0..4 (lanes >=40 inactive)
    const int j = lane & 7;        // member within group
    const bool act = lane < NG * KK;

    int vid = 0;
    if (act) vid = (g == 0) ? edge_members[e * KK + j]
                            : adj_members[((e * RR) + (g - 1)) * KK + j];

    const float4 qkv = qkv4[vid];
    const float2 pf  = pfc2[vid];

    // all-gather k,v of the 8 group members via shfl (bpermute)
    float k8[KK], v8[KK];
    #pragma unroll
    for (int r = 0; r < KK; ++r) {
        k8[r] = __shfl(qkv.y, (g << 3) + r);
        v8[r] = __shfl(qkv.z, (g << 3) + r);
    }

    // masked softmax over r != j, tanh gate
    float mx = -1e30f;
    float s[KK];
    #pragma unroll
    for (int r = 0; r < KK; ++r) {
        s[r] = qkv.x * k8[r];
        if (r != j) mx = fmaxf(mx, s[r]);
    }
    float den = 0.f, num = 0.f;
    #pragma unroll
    for (int r = 0; r < KK; ++r) {
        if (r == j) continue;
        const float ex = expf(s[r] - mx);
        den += ex;
        num += ex * v8[r];
    }
    const float di = tanhf(num / den);

    // ftfc[g][c] = sum_j di_j * pfc[vid_j][c]  (reduce within 8-lane group)
    float px = di * pf.x, py = di * pf.y;
    #pragma unroll
    for (int mm = 4; mm >= 1; mm >>= 1) {
        px += __shfl_xor(px, mm);
        py += __shfl_xor(py, mm);
    }
    if (act) {
        vidS[w][lane] = vid;
        diS[w][lane]  = di;
        if (j == 0) { ftfcS[w][g][0] = px; ftfcS[w][g][1] = py; }
    }
    asm volatile("s_waitcnt lgkmcnt(0)" ::: "memory");

    // EdgeConv scores: relu(sum_j di*P1[vid_j] + b1) @ W2 + b2, two groups per pass
    const float b1m = b1[lane & 31];
    const float w2m = W2[lane & 31];
    #pragma unroll
    for (int p = 0; p < 3; ++p) {
        const int grp = (p << 1) | (lane >> 5);
        const int m = lane & 31;
        if (grp < NG) {
            float dr[KK]; float pv1[KK];
            #pragma unroll
            for (int r = 0; r < KK; ++r) {
                const int vr = vidS[w][grp * KK + r];     // broadcast ds_read
                dr[r] = diS[w][grp * KK + r];
                pv1[r] = P1[(long long)vr * HID + m];     // coalesced 128B per r
            }
            float acc = 0.f;
            #pragma unroll
            for (int r = 0; r < KK; ++r) acc += dr[r] * pv1[r];
            float hid = fmaxf(acc + b1m, 0.f) * w2m;
            #pragma unroll
            for (int mm = 16; mm >= 1; mm >>= 1) hid += __shfl_xor(hid, mm);
            if (m == 0) scS[w][grp] = hid + b2[0];
        }
    }
    asm volatile("s_waitcnt lgkmcnt(0)" ::: "memory");

    // softmax over 5 candidates + final sigmoid(Linear) ; lanes 0..1 (c = lane)
    if (lane < 2) {
        float sc0[NG];
        float m5 = -1e30f;
        #pragma unroll
        for (int gg = 0; gg < NG; ++gg) { sc0[gg] = scS[w][gg]; m5 = fmaxf(m5, sc0[gg]); }
        float ssum = 0.f;
        #pragma unroll
        for (int gg = 0; gg < NG; ++gg) { sc0[gg] = expf(sc0[gg] - m5); ssum += sc0[gg]; }
        const float inv = 1.f / ssum;
        float hc = 0.f;
        #pragma unroll
        for (int gg = 0; gg < NG; ++gg) hc += sc0[gg] * inv * ftfcS[w][gg][lane];
        const float z = hc + bfc[lane];
        out[e * 2 + lane] = 1.f / (1.f + expf(-z));
    }
}

extern "C" void kernel_launch(void* const* d_in, const int* in_sizes, int n_in,
                              void* d_out, int out_size, void* d_ws, size_t ws_size,
                              hipStream_t stream) {
    const float* feats        = (const float*)d_in[0];
    const int*   edge_members = (const int*)  d_in[1];
    const int*   adj_members  = (const int*)  d_in[2];
    // d_in[3] = ids (unused), d_in[4] = epoch (unused; epoch=10 >= both warmups)
    const float* wq  = (const float*)d_in[5];
    const float* bq  = (const float*)d_in[6];
    const float* wk  = (const float*)d_in[7];
    const float* bk  = (const float*)d_in[8];
    const float* wv  = (const float*)d_in[9];
    const float* bv  = (const float*)d_in[10];
    const float* W1  = (const float*)d_in[11];
    const float* b1  = (const float*)d_in[12];
    const float* W2  = (const float*)d_in[13];
    const float* b2  = (const float*)d_in[14];
    const float* Wfc = (const float*)d_in[15];
    const float* bfc = (const float*)d_in[16];
    float* out = (float*)d_out;

    const int n_vert = in_sizes[0] / DD;   // 100000
    const int n_edge = in_sizes[1] / KK;   // 20000

    // workspace layout (all 16B-aligned)
    char* ws = (char*)d_ws;
    float4* qkv4 = (float4*)ws;                                    // n_vert*16 B
    float2* pfc2 = (float2*)(ws + (size_t)n_vert * 16);            // n_vert*8 B
    float*  P1   = (float*) (ws + (size_t)n_vert * 24);            // n_vert*128 B

    precompute_proj<<<(n_vert + 7) / 8, 256, 0, stream>>>(
        feats, n_vert, wq, bq, wk, bk, wv, bv, W1, Wfc, qkv4, pfc2, P1);

    edge_fused<<<(n_edge + 3) / 4, 256, 0, stream>>>(
        edge_members, adj_members, qkv4, pfc2, P1, b1, W2, b2, bfc, out, n_edge);
}

// Round 4
// 68.061 us; speedup vs baseline: 2.5888x; 1.2796x over previous
//
#include <hip/hip_runtime.h>
#include <math.h>

#define KK 8
#define DD 128
#define RR 4
#define NG 5     // 1 + R groups per edge
#define HID 32   // D/4 hidden units
#define NC 40    // proj columns: 0..2 q/k/v, 3..4 Wfc, 5..36 W1, 37..39 pad
#define VPB 32   // vertices per block in proj kernel
#define PITCH 132 // LDS row pitch in floats (bank-conflict-free b128)

// ---------------- Kernel A: proj[v] = f_v @ [wq|wk|wv|Wfc|W1] ----------------
__global__ __launch_bounds__(256) void proj_kernel(
    const float* __restrict__ feats, int n_vert,
    const float* __restrict__ wq, const float* __restrict__ bq,
    const float* __restrict__ wk, const float* __restrict__ bk,
    const float* __restrict__ wv, const float* __restrict__ bv,
    const float* __restrict__ W1, const float* __restrict__ Wfc,
    float* __restrict__ proj)
{
    __shared__ float Wt[NC][PITCH];    // 21.1 KB  transposed weights
    __shared__ float fsh[VPB][PITCH];  // 16.9 KB  32 vertex rows

    const int t = threadIdx.x;
    const long long vbase = (long long)blockIdx.x * VPB;

    // stage W1^T : Wt[5+m][d] = W1[d*32+m]  (coalesced global reads)
    #pragma unroll
    for (int k = 0; k < 16; ++k) {
        const int idx = t + k * 256;           // 4096 elements
        Wt[5 + (idx & 31)][idx >> 5] = W1[idx];
    }
    if (t < 128) {
        Wt[0][t] = wq[t];
        Wt[1][t] = wk[t];
        Wt[2][t] = wv[t];
        Wt[3][t] = Wfc[t * 2 + 0];
        Wt[4][t] = Wfc[t * 2 + 1];
    } else {
        // zero pad rows 37..39 (3*PITCH = 396 words)
        const int i = t - 128;
        float* z = &Wt[37][0];
        #pragma unroll
        for (int k = 0; k < 4; ++k) {
            const int zi = i + k * 128;
            if (zi < 3 * PITCH) z[zi] = 0.f;
        }
    }

    // stage 32 vertex rows, fully coalesced
    #pragma unroll
    for (int k = 0; k < 4; ++k) {
        const int f4i = t + k * 256;           // 1024 float4s
        const int word = f4i * 4;
        const int row = word >> 7;
        const int col = word & 127;
        long long gv = vbase + row;
        if (gv >= n_vert) gv = n_vert - 1;
        *(float4*)&fsh[row][col] = *(const float4*)&feats[gv * DD + col];
    }
    __syncthreads();

    // thread owns (vertex vslot, columns c0, c0+8, ..., c0+32)
    const int vslot = t >> 3;
    const int c0 = t & 7;
    float acc0 = 0.f, acc1 = 0.f, acc2 = 0.f, acc3 = 0.f, acc4 = 0.f;
    #pragma unroll 8
    for (int ch = 0; ch < 32; ++ch) {
        const float4 f4 = *(const float4*)&fsh[vslot][ch * 4];
        const float4 w0 = *(const float4*)&Wt[c0     ][ch * 4];
        const float4 w1 = *(const float4*)&Wt[c0 +  8][ch * 4];
        const float4 w2 = *(const float4*)&Wt[c0 + 16][ch * 4];
        const float4 w3 = *(const float4*)&Wt[c0 + 24][ch * 4];
        const float4 w4 = *(const float4*)&Wt[c0 + 32][ch * 4];
        acc0 += f4.x*w0.x + f4.y*w0.y + f4.z*w0.z + f4.w*w0.w;
        acc1 += f4.x*w1.x + f4.y*w1.y + f4.z*w1.z + f4.w*w1.w;
        acc2 += f4.x*w2.x + f4.y*w2.y + f4.z*w2.z + f4.w*w2.w;
        acc3 += f4.x*w3.x + f4.y*w3.y + f4.z*w3.z + f4.w*w3.w;
        acc4 += f4.x*w4.x + f4.y*w4.y + f4.z*w4.z + f4.w*w4.w;
    }
    if      (c0 == 0) acc0 += bq[0];
    else if (c0 == 1) acc0 += bk[0];
    else if (c0 == 2) acc0 += bv[0];

    const long long v = vbase + vslot;
    if (v < n_vert) {
        float* pr = &proj[v * NC];
        pr[c0]      = acc0;
        pr[c0 + 8]  = acc1;
        pr[c0 + 16] = acc2;
        pr[c0 + 24] = acc3;
        if (c0 < 5) pr[c0 + 32] = acc4;   // cols 32..36 only
    }
}

// ---------------- Kernel B: per-edge fusion (one wave per edge) ----------------
__global__ __launch_bounds__(256) void edge_fused(
    const int* __restrict__ edge_members,
    const int* __restrict__ adj_members,
    const float* __restrict__ proj,
    const float* __restrict__ b1, const float* __restrict__ W2,
    const float* __restrict__ b2, const float* __restrict__ bfc,
    float* __restrict__ out, int n_edge)
{
    __shared__ int   vidS[4][NG * KK];
    __shared__ float diS [4][NG * KK];
    __shared__ float ftfcS[4][NG][2];
    __shared__ float scS [4][NG];

    const int t = threadIdx.x;
    const int w = t >> 6;          // wave in block
    const int lane = t & 63;
    const int e = blockIdx.x * 4 + w;
    if (e >= n_edge) return;

    const int g = lane >> 3;       // group 0..4 (lanes >=40 inactive)
    const int j = lane & 7;        // member within group
    const bool act = lane < NG * KK;

    int vid = 0;
    if (act) vid = (g == 0) ? edge_members[e * KK + j]
                            : adj_members[((e * RR) + (g - 1)) * KK + j];

    const float4 qp = *(const float4*)&proj[(long long)vid * NC]; // q,k,v,pfc0
    const float  pf1 = proj[(long long)vid * NC + 4];             // pfc1

    // all-gather k,v of the 8 group members via shfl
    float k8[KK], v8[KK];
    #pragma unroll
    for (int r = 0; r < KK; ++r) {
        k8[r] = __shfl(qp.y, (g << 3) + r);
        v8[r] = __shfl(qp.z, (g << 3) + r);
    }

    // masked softmax over r != j, tanh gate
    float mx = -1e30f;
    float s[KK];
    #pragma unroll
    for (int r = 0; r < KK; ++r) {
        s[r] = qp.x * k8[r];
        if (r != j) mx = fmaxf(mx, s[r]);
    }
    float den = 0.f, num = 0.f;
    #pragma unroll
    for (int r = 0; r < KK; ++r) {
        if (r == j) continue;
        const float ex = expf(s[r] - mx);
        den += ex;
        num += ex * v8[r];
    }
    const float di = tanhf(num / den);

    // ftfc[g][c] = sum_j di_j * pfc[vid_j][c]
    float px = di * qp.w, py = di * pf1;
    #pragma unroll
    for (int mm = 4; mm >= 1; mm >>= 1) {
        px += __shfl_xor(px, mm);
        py += __shfl_xor(py, mm);
    }
    if (act) {
        vidS[w][lane] = vid;
        diS[w][lane]  = di;
        if (j == 0) { ftfcS[w][g][0] = px; ftfcS[w][g][1] = py; }
    }
    asm volatile("s_waitcnt lgkmcnt(0)" ::: "memory");

    // EdgeConv scores: relu(sum_j di*P1[vid_j] + b1) @ W2 + b2
    const float b1m = b1[lane & 31];
    const float w2m = W2[lane & 31];
    #pragma unroll
    for (int p = 0; p < 3; ++p) {
        const int grp = (p << 1) | (lane >> 5);
        const int m = lane & 31;
        if (grp < NG) {
            float dr[KK]; float pv1[KK];
            #pragma unroll
            for (int r = 0; r < KK; ++r) {
                const int vr = vidS[w][grp * KK + r];
                dr[r]  = diS[w][grp * KK + r];
                pv1[r] = proj[(long long)vr * NC + 5 + m];   // coalesced 128B
            }
            float acc = 0.f;
            #pragma unroll
            for (int r = 0; r < KK; ++r) acc += dr[r] * pv1[r];
            float hid = fmaxf(acc + b1m, 0.f) * w2m;
            #pragma unroll
            for (int mm = 16; mm >= 1; mm >>= 1) hid += __shfl_xor(hid, mm);
            if (m == 0) scS[w][grp] = hid + b2[0];
        }
    }
    asm volatile("s_waitcnt lgkmcnt(0)" ::: "memory");

    // softmax over 5 candidates + final sigmoid(Linear)
    if (lane < 2) {
        float sc0[NG];
        float m5 = -1e30f;
        #pragma unroll
        for (int gg = 0; gg < NG; ++gg) { sc0[gg] = scS[w][gg]; m5 = fmaxf(m5, sc0[gg]); }
        float ssum = 0.f;
        #pragma unroll
        for (int gg = 0; gg < NG; ++gg) { sc0[gg] = expf(sc0[gg] - m5); ssum += sc0[gg]; }
        const float inv = 1.f / ssum;
        float hc = 0.f;
        #pragma unroll
        for (int gg = 0; gg < NG; ++gg) hc += sc0[gg] * inv * ftfcS[w][gg][lane];
        const float z = hc + bfc[lane];
        out[e * 2 + lane] = 1.f / (1.f + expf(-z));
    }
}

extern "C" void kernel_launch(void* const* d_in, const int* in_sizes, int n_in,
                              void* d_out, int out_size, void* d_ws, size_t ws_size,
                              hipStream_t stream) {
    const float* feats        = (const float*)d_in[0];
    const int*   edge_members = (const int*)  d_in[1];
    const int*   adj_members  = (const int*)  d_in[2];
    // d_in[3] = ids (unused), d_in[4] = epoch (unused; epoch=10 >= both warmups)
    const float* wq  = (const float*)d_in[5];
    const float* bq  = (const float*)d_in[6];
    const float* wk  = (const float*)d_in[7];
    const float* bk  = (const float*)d_in[8];
    const float* wv  = (const float*)d_in[9];
    const float* bv  = (const float*)d_in[10];
    const float* W1  = (const float*)d_in[11];
    const float* b1  = (const float*)d_in[12];
    const float* W2  = (const float*)d_in[13];
    const float* b2  = (const float*)d_in[14];
    const float* Wfc = (const float*)d_in[15];
    const float* bfc = (const float*)d_in[16];
    float* out = (float*)d_out;

    const int n_vert = in_sizes[0] / DD;   // 100000
    const int n_edge = in_sizes[1] / KK;   // 20000

    float* proj = (float*)d_ws;            // n_vert * 40 floats = 16 MB

    proj_kernel<<<(n_vert + VPB - 1) / VPB, 256, 0, stream>>>(
        feats, n_vert, wq, bq, wk, bk, wv, bv, W1, Wfc, proj);

    edge_fused<<<(n_edge + 3) / 4, 256, 0, stream>>>(
        edge_members, adj_members, proj, b1, W2, b2, bfc, out, n_edge);
}